// Round 1
// baseline (1349.451 us; speedup 1.0000x reference)
//
#include <hip/hip_runtime.h>
#include <math.h>

#define N_B 16
#define T_LEN 4096

typedef float f32x4  __attribute__((ext_vector_type(4)));
typedef _Float16 half8 __attribute__((ext_vector_type(8)));

// ---- workspace layout (float offsets) — r4-proven fit ----
static const size_t OFF_A    = 0;            // 16*128*4096
static const size_t OFF_B    = 8388608;      // 16*256*4096
static const size_t OFF_Z    = 25165824;     // 16*64*4096
static const size_t OFF_WT1  = 29360128;
static const size_t OFF_WT2  = 29390848;
static const size_t OFF_WT3  = 29489152;
static const size_t OFF_WD1  = 29505536;
static const size_t OFF_WD2  = 29554688;
static const size_t OFF_WD3  = 29652992;
static const size_t OFF_C2   = 29683712;
static const size_t OFF_ST   = 29684736;
static const size_t OFF_LOSS = 29685760;

// scaled f16 split: v = hi + lo * 2^-12, error ~2^-24 relative (f32-grade).
// Scaling by 4096 keeps lo in f16 normal range for all magnitudes seen here.
__device__ inline void f2h2(float v, short& hi, short& lo) {
    _Float16 h = (_Float16)v;
    float r = (v - (float)h) * 4096.0f;
    _Float16 l = (_Float16)r;
    hi = __builtin_bit_cast(short, h);
    lo = __builtin_bit_cast(short, l);
}

// ---- weight transpose helper: w[CO][CI][KS] -> wT[KS][CI][CO] (f32) ----
template<int C_OUT, int C_IN, int KS>
__device__ inline void tw(const float* __restrict__ w, float* __restrict__ wT, int e) {
    int co  = e / (C_IN * KS);
    int rem = e - co * (C_IN * KS);
    int ci  = rem / KS;
    int k   = rem - ci * KS;
    wT[(k * C_IN + ci) * C_OUT + co] = w[e];
}

__global__ __launch_bounds__(256) void prep_k(
        const float* __restrict__ w1, const float* __restrict__ w2,
        const float* __restrict__ w3, const float* __restrict__ wd1,
        const float* __restrict__ wd2, const float* __restrict__ wd3,
        const float* __restrict__ cb, float* wsf) {
    int e = blockIdx.x * 256 + threadIdx.x;
    if (e < 30720)        tw<128,  80, 3>(w1,  wsf + OFF_WT1, e);
    else if (e < 129024)  tw<256, 128, 3>(w2,  wsf + OFF_WT2, e - 30720);
    else if (e < 145408)  tw< 64, 256, 1>(w3,  wsf + OFF_WT3, e - 129024);
    else if (e < 194560)  tw<256,  64, 3>(wd1, wsf + OFF_WD1, e - 145408);
    else if (e < 292864)  tw<128, 256, 3>(wd2, wsf + OFF_WD2, e - 194560);
    else if (e < 323584)  tw< 80, 128, 3>(wd3, wsf + OFF_WD3, e - 292864);
    else if (e < 324096) {
        int c = e - 323584;
        const float* p = cb + (size_t)c * 64;
        double s = 0.0;
        for (int d = 0; d < 64; ++d) { double v = p[d]; s += v * v; }
        wsf[OFF_C2 + c] = (float)s;
    } else if (e == 324096) {
        *(double*)(wsf + OFF_LOSS) = 0.0;
    }
}

// ---- unified conv1d via scaled-f16 split MFMA (f32-grade precision) ----
// GEMM M=co, N=t, K=ci per k-tap. Block: 64co x 64t, 4 waves (wave=16co strip).
// gfx950 16x16x32 maps (m89/m120-verified): A[m=lane&15][k=q*8+j],
// B[k=q*8+j][n=lane&15], D[m=q*4+r][n=lane&15]. Integer probe verifies; on
// mismatch a plain-f32 VALU path computes from the same LDS tiles.
// acc0 += ah*bh ; acc1 += ah*bl + al*bh ; out = acc0 + acc1/4096.
template<int C_IN, int C_OUT, int KS, bool BN_IN>
__global__ __launch_bounds__(256) void fconv_k(
        const float* __restrict__ x, const float* __restrict__ wT,
        const float* __restrict__ bias, const double2* __restrict__ stats,
        float* __restrict__ out) {
    constexpr int CI_CH = 32;
    constexpr int RS    = 72;       // row stride in shorts (144B, 16B-aligned)
    constexpr int LO    = 40;       // lo-plane offset within row (80B)
    constexpr int HALO  = KS / 2;
    constexpr int XR    = 64 + KS - 1;

    __shared__ __align__(16) short xs[XR * RS];       // t rows
    __shared__ __align__(16) short ws[KS * 64 * RS];  // (k*64+co) rows
    __shared__ int okf;

    const int tid  = threadIdx.x;
    const int lane = tid & 63;
    const int wv   = tid >> 6;
    const int ln   = lane & 15;
    const int q    = lane >> 4;

    const int n   = blockIdx.x >> 6;
    const int t0  = (blockIdx.x & 63) * 64;
    const int co0 = blockIdx.y * 64;

    // ---- layout verify probe (exact integers in f16/f32) ----
    bool ok = true;
    {
        half8 pa, pb;
#pragma unroll
        for (int j = 0; j < 8; ++j) {
            int kk = q * 8 + j;
            pa[j] = (_Float16)(float)(ln + 2 * kk);
            pb[j] = (_Float16)(float)(ln + 3 * kk);
        }
        f32x4 pd = {0.f, 0.f, 0.f, 0.f};
        pd = __builtin_amdgcn_mfma_f32_16x16x32_f16(pa, pb, pd, 0, 0, 0);
#pragma unroll
        for (int r = 0; r < 4; ++r) {
            int m = q * 4 + r;
            float e = (float)(32 * m * ln + 1488 * m + 992 * ln + 62496);
            if (pd[r] != e) ok = false;
        }
    }
    if (tid == 0) okf = 1;
    __syncthreads();
    if (!ok) okf = 0;
    __syncthreads();
    const bool okp = (okf != 0);

    f32x4 a0[4], a1[4];
#pragma unroll
    for (int tt = 0; tt < 4; ++tt)
#pragma unroll
        for (int i = 0; i < 4; ++i) { a0[tt][i] = 0.f; a1[tt][i] = 0.f; }

    for (int ci0 = 0; ci0 < C_IN; ci0 += CI_CH) {
        __syncthreads();
        // stage x: rows trow (t = t0-HALO+trow), cols ci (hi) / LO+ci (lo)
        for (int e = tid; e < CI_CH * XR; e += 256) {
            int ci   = e / XR;
            int trow = e - ci * XR;
            int gt   = t0 - HALO + trow;
            int cig  = ci0 + ci;
            float v  = 0.f;
            if (cig < C_IN && gt >= 0 && gt < T_LEN) {
                v = x[((size_t)(n * C_IN + cig)) * T_LEN + gt];
                if constexpr (BN_IN) {
                    double2 s = stats[cig];
                    v = (float)fmax(fma((double)v, s.x, s.y), 0.0);
                }
            }
            short h, l; f2h2(v, h, l);
            xs[trow * RS + ci]      = h;
            xs[trow * RS + LO + ci] = l;
        }
        // stage w: rows (k*64+co); zero-pad co >= C_OUT and ci >= C_IN
        for (int e = tid; e < KS * CI_CH * 64; e += 256) {
            int co = e & 63;
            int rr = e >> 6;           // k*32+ci
            int k  = rr >> 5;
            int ci = rr & 31;
            float v = 0.f;
            if (ci0 + ci < C_IN && co0 + co < C_OUT)
                v = wT[((size_t)(k * C_IN + ci0 + ci)) * C_OUT + co0 + co];
            short h, l; f2h2(v, h, l);
            ws[(k * 64 + co) * RS + ci]      = h;
            ws[(k * 64 + co) * RS + LO + ci] = l;
        }
        __syncthreads();

        if (okp) {
#pragma unroll
            for (int k = 0; k < KS; ++k) {
                const short* wr = &ws[(k * 64 + wv * 16 + ln) * RS + q * 8];
                half8 ah = *(const half8*)&wr[0];
                half8 al = *(const half8*)&wr[LO];
#pragma unroll
                for (int tt = 0; tt < 4; ++tt) {
                    const short* xr = &xs[(tt * 16 + ln + k) * RS + q * 8];
                    half8 bh = *(const half8*)&xr[0];
                    half8 bl = *(const half8*)&xr[LO];
                    a0[tt] = __builtin_amdgcn_mfma_f32_16x16x32_f16(ah, bh, a0[tt], 0, 0, 0);
                    a1[tt] = __builtin_amdgcn_mfma_f32_16x16x32_f16(ah, bl, a1[tt], 0, 0, 0);
                    a1[tt] = __builtin_amdgcn_mfma_f32_16x16x32_f16(al, bh, a1[tt], 0, 0, 0);
                }
            }
        } else {
            // plain-f32 fallback from same tiles; acc matches D-map (m=q*4+r)
            for (int k = 0; k < KS; ++k)
                for (int ci = 0; ci < CI_CH; ++ci) {
                    float wr[4], xv[4];
#pragma unroll
                    for (int r = 0; r < 4; ++r) {
                        const short* p = &ws[(k * 64 + wv * 16 + q * 4 + r) * RS];
                        wr[r] = (float)__builtin_bit_cast(_Float16, p[ci])
                              + (float)__builtin_bit_cast(_Float16, p[LO + ci]) * 0.000244140625f;
                    }
#pragma unroll
                    for (int tt = 0; tt < 4; ++tt) {
                        const short* p = &xs[(tt * 16 + ln + k) * RS];
                        xv[tt] = (float)__builtin_bit_cast(_Float16, p[ci])
                               + (float)__builtin_bit_cast(_Float16, p[LO + ci]) * 0.000244140625f;
                    }
#pragma unroll
                    for (int tt = 0; tt < 4; ++tt)
#pragma unroll
                        for (int r = 0; r < 4; ++r)
                            a0[tt][r] = fmaf(wr[r], xv[tt], a0[tt][r]);
                }
        }
    }

    // epilogue: lane reg r -> D[co = co0+wv*16+q*4+r][t = t0+tt*16+ln]
#pragma unroll
    for (int tt = 0; tt < 4; ++tt) {
#pragma unroll
        for (int r = 0; r < 4; ++r) {
            int co = co0 + wv * 16 + q * 4 + r;
            if (co < C_OUT)
                out[((size_t)(n * C_OUT + co)) * T_LEN + t0 + tt * 16 + ln] =
                    fmaf(a1[tt][r], 0.000244140625f, a0[tt][r]) + bias[co];
        }
    }
}

// ---- BN stats stage 1 ----
__global__ __launch_bounds__(256) void stats1_k(
        const float* __restrict__ y, int C, double2* __restrict__ part) {
    int c = blockIdx.x % C, n = blockIdx.x / C;
    int tid = threadIdx.x;
    const float* p = y + ((size_t)(n * C + c)) * T_LEN;
    double s1 = 0.0, s2 = 0.0;
    for (int t = tid; t < T_LEN; t += 256) {
        double v = p[t];
        s1 += v; s2 += v * v;
    }
    __shared__ double r1[256], r2[256];
    r1[tid] = s1; r2[tid] = s2;
    __syncthreads();
    for (int s = 128; s > 0; s >>= 1) {
        if (tid < s) { r1[tid] += r1[tid + s]; r2[tid] += r2[tid + s]; }
        __syncthreads();
    }
    if (tid == 0) part[(size_t)c * N_B + n] = make_double2(r1[0], r2[0]);
}

// ---- BN stats stage 2 ----
__global__ __launch_bounds__(256) void stats2_k(
        const double2* __restrict__ part, int C, const float* __restrict__ g,
        const float* __restrict__ b, double2* __restrict__ stats) {
    int c = blockIdx.x * 256 + threadIdx.x;
    if (c >= C) return;
    double s1 = 0.0, s2 = 0.0;
    for (int n = 0; n < N_B; ++n) {
        double2 v = part[(size_t)c * N_B + n];
        s1 += v.x; s2 += v.y;
    }
    double m   = s1 / 65536.0;
    double var = s2 / 65536.0 - m * m;
    double sc  = (double)g[c] / sqrt(var + 1e-5);
    stats[c] = make_double2(sc, (double)b[c] - m * sc);
}

// ---- VQ: replicate the reference's f32 d2 formula exactly ----
__global__ __launch_bounds__(256) void vq_k(
        const float* z, const float* __restrict__ cb,
        const float* __restrict__ c2, float* q,
        float* __restrict__ idx_out, double* __restrict__ loss) {
    __shared__ __align__(16) float zs[64 * 68];
    __shared__ __align__(16) float cs[64 * 68];
    __shared__ float  szf[64];
    __shared__ float  redS[64 * 16];
    __shared__ int    redI[64 * 16];
    __shared__ int    idxs[64];
    __shared__ double dred[256];

    const int tid = threadIdx.x;
    const int tx  = tid & 15, ty = tid >> 4;
    const int n   = blockIdx.x >> 6;
    const int t0  = (blockIdx.x & 63) * 64;

    for (int e = tid; e < 4096; e += 256) {
        int t = e & 63, d = e >> 6;
        zs[t * 68 + d] = z[((size_t)(n * 64 + d)) * T_LEN + t0 + t];
    }
    __syncthreads();
    if (tid < 64) {
        double s = 0.0;
        const float* zr = &zs[tid * 68];
        for (int d = 0; d < 64; ++d) { double v = zr[d]; s += v * v; }
        szf[tid] = (float)s;
    }

    float best[4];
    int bidx[4];
#pragma unroll
    for (int i = 0; i < 4; ++i) { best[i] = 3.0e38f; bidx[i] = 1 << 30; }

    for (int ch = 0; ch < 8; ++ch) {
        __syncthreads();
        for (int e = tid; e < 4096; e += 256) {
            int d = e & 63, c = e >> 6;
            cs[c * 68 + d] = cb[((size_t)(ch * 64 + c)) * 64 + d];
        }
        __syncthreads();

        double acc[4][4];
#pragma unroll
        for (int i = 0; i < 4; ++i)
#pragma unroll
            for (int j = 0; j < 4; ++j) acc[i][j] = 0.0;

        for (int d = 0; d < 64; d += 4) {
            float4 zv[4], cv[4];
#pragma unroll
            for (int i = 0; i < 4; ++i)
                zv[i] = *(const float4*)&zs[(tx + 16 * i) * 68 + d];
#pragma unroll
            for (int j = 0; j < 4; ++j)
                cv[j] = *(const float4*)&cs[(ty + 16 * j) * 68 + d];
#pragma unroll
            for (int i = 0; i < 4; ++i)
#pragma unroll
                for (int j = 0; j < 4; ++j) {
                    acc[i][j] = fma((double)zv[i].x, (double)cv[j].x, acc[i][j]);
                    acc[i][j] = fma((double)zv[i].y, (double)cv[j].y, acc[i][j]);
                    acc[i][j] = fma((double)zv[i].z, (double)cv[j].z, acc[i][j]);
                    acc[i][j] = fma((double)zv[i].w, (double)cv[j].w, acc[i][j]);
                }
        }
#pragma unroll
        for (int j = 0; j < 4; ++j) {
            int cg = ch * 64 + ty + 16 * j;
            float cc = c2[cg];
#pragma unroll
            for (int i = 0; i < 4; ++i) {
                float m32 = (float)acc[i][j];
                float A   = szf[tx + 16 * i] + cc;
                float s   = A - 2.0f * m32;
                if (s < best[i] || (s == best[i] && cg < bidx[i])) {
                    best[i] = s; bidx[i] = cg;
                }
            }
        }
    }
#pragma unroll
    for (int i = 0; i < 4; ++i) {
        redS[(tx + 16 * i) * 16 + ty] = best[i];
        redI[(tx + 16 * i) * 16 + ty] = bidx[i];
    }
    __syncthreads();

    if (tid < 64) {
        int t = tid;
        float bs = 3.0e38f; int bi = 1 << 30;
        for (int y2 = 0; y2 < 16; ++y2) {
            float v = redS[t * 16 + y2];
            int vi  = redI[t * 16 + y2];
            if (v < bs || (v == bs && vi < bi)) { bs = v; bi = vi; }
        }
        idxs[t] = bi;
        idx_out[(size_t)n * T_LEN + t0 + t] = (float)bi;
    }
    __syncthreads();

    {
        int g = tid >> 6, t = tid & 63;
        int bi = idxs[t];
        double ls = 0.0;
        for (int dd = 0; dd < 16; ++dd) {
            int d = g * 16 + dd;
            float qv = cb[(size_t)bi * 64 + d];
            float zv = zs[t * 68 + d];
            double df = (double)qv - (double)zv;
            ls += df * df;
            q[((size_t)(n * 64 + d)) * T_LEN + t0 + t] = qv;
        }
        dred[tid] = ls;
    }
    __syncthreads();
    for (int s = 128; s > 0; s >>= 1) {
        if (tid < s) dred[tid] += dred[tid + s];
        __syncthreads();
    }
    if (tid == 0) atomicAdd(loss, dred[0]);
}

__global__ void fin_k(const double* __restrict__ loss, float* __restrict__ out) {
    if (threadIdx.x == 0 && blockIdx.x == 0)
        out[0] = (float)(1.25 * (*loss) / 4194304.0);
}

extern "C" void kernel_launch(void* const* d_in, const int* in_sizes, int n_in,
                              void* d_out, int out_size, void* d_ws, size_t ws_size,
                              hipStream_t stream) {
    const float* x      = (const float*)d_in[0];
    const float* enc_w1 = (const float*)d_in[1];
    const float* enc_b1 = (const float*)d_in[2];
    const float* bn1_g  = (const float*)d_in[3];
    const float* bn1_b  = (const float*)d_in[4];
    const float* enc_w2 = (const float*)d_in[5];
    const float* enc_b2 = (const float*)d_in[6];
    const float* bn2_g  = (const float*)d_in[7];
    const float* bn2_b  = (const float*)d_in[8];
    const float* enc_w3 = (const float*)d_in[9];
    const float* enc_b3 = (const float*)d_in[10];
    const float* cb     = (const float*)d_in[11];
    const float* dec_w1 = (const float*)d_in[12];
    const float* dec_b1 = (const float*)d_in[13];
    const float* dbn1_g = (const float*)d_in[14];
    const float* dbn1_b = (const float*)d_in[15];
    const float* dec_w2 = (const float*)d_in[16];
    const float* dec_b2 = (const float*)d_in[17];
    const float* dbn2_g = (const float*)d_in[18];
    const float* dbn2_b = (const float*)d_in[19];
    const float* dec_w3 = (const float*)d_in[20];
    const float* dec_b3 = (const float*)d_in[21];

    float* wsf   = (float*)d_ws;
    float* outf  = (float*)d_out;
    float* A     = wsf + OFF_A;
    float* Bb    = wsf + OFF_B;
    float* Z     = wsf + OFF_Z;
    double2* st  = (double2*)(wsf + OFF_ST);
    double* lossp = (double*)(wsf + OFF_LOSS);
    double2* partA = (double2*)A;
    double2* partB = (double2*)Bb;

    prep_k<<<1268, 256, 0, stream>>>(enc_w1, enc_w2, enc_w3,
                                     dec_w1, dec_w2, dec_w3, cb, wsf);

    // encoder: scaled-f16 split MFMA (f32-grade precision)
    fconv_k<80, 128, 3, false><<<dim3(1024, 2), 256, 0, stream>>>(
        x, wsf + OFF_WT1, enc_b1, nullptr, A);
    stats1_k<<<128 * N_B, 256, 0, stream>>>(A, 128, partB);
    stats2_k<<<1, 256, 0, stream>>>(partB, 128, bn1_g, bn1_b, st);
    fconv_k<128, 256, 3, true><<<dim3(1024, 4), 256, 0, stream>>>(
        A, wsf + OFF_WT2, enc_b2, st, Bb);
    stats1_k<<<256 * N_B, 256, 0, stream>>>(Bb, 256, partA);
    stats2_k<<<1, 256, 0, stream>>>(partA, 256, bn2_g, bn2_b, st);
    fconv_k<256, 64, 1, true><<<dim3(1024, 1), 256, 0, stream>>>(
        Bb, wsf + OFF_WT3, enc_b3, st, Z);

    // vector quantizer — f32-formula scores, exact ref grid
    vq_k<<<1024, 256, 0, stream>>>(Z, cb, wsf + OFF_C2, Z,
                                   outf + 5242881, lossp);
    fin_k<<<1, 64, 0, stream>>>(lossp, outf + 5242880);

    // decoder: same unified kernel (precision upgrade vs old bf16 split)
    fconv_k<64, 256, 3, false><<<dim3(1024, 4), 256, 0, stream>>>(
        Z, wsf + OFF_WD1, dec_b1, nullptr, Bb);
    stats1_k<<<256 * N_B, 256, 0, stream>>>(Bb, 256, partA);
    stats2_k<<<1, 256, 0, stream>>>(partA, 256, dbn1_g, dbn1_b, st);
    fconv_k<256, 128, 3, true><<<dim3(1024, 2), 256, 0, stream>>>(
        Bb, wsf + OFF_WD2, dec_b2, st, A);
    stats1_k<<<128 * N_B, 256, 0, stream>>>(A, 128, partB);
    stats2_k<<<1, 256, 0, stream>>>(partB, 128, dbn2_g, dbn2_b, st);
    fconv_k<128, 80, 3, true><<<dim3(1024, 2), 256, 0, stream>>>(
        A, wsf + OFF_WD3, dec_b3, st, outf);
}

// Round 2
// 510.855 us; speedup vs baseline: 2.6416x; 2.6416x over previous
//
#include <hip/hip_runtime.h>
#include <math.h>

#define N_B 16
#define T_LEN 4096

typedef float f32x4  __attribute__((ext_vector_type(4)));
typedef _Float16 half8 __attribute__((ext_vector_type(8)));

// ---- workspace layout (float offsets) — high-water mark unchanged vs r4 ----
static const size_t OFF_A    = 0;            // 16*128*4096
static const size_t OFF_B    = 8388608;      // 16*256*4096
static const size_t OFF_Z    = 25165824;     // 16*64*4096
static const size_t OFF_WS   = 29360128;     // split-weight region (<=323584 floats)
static const size_t OFF_C2   = 29683712;
static const size_t OFF_ST   = 29684736;
static const size_t OFF_LOSS = 29685760;

// encoder split offsets (floats from OFF_WS); region reused by decoder after conv3
static const size_t WS_E1 = 0;        // 3*3*128*32 elems = 36864 floats
static const size_t WS_E2 = 36864;    // 4*3*256*32       = 98304 floats
static const size_t WS_E3 = 135168;   // 8*1*64*32        = 16384 floats -> end 151552
static const size_t WS_D1 = 0;        // 2*3*256*32       = 49152 floats
static const size_t WS_D2 = 49152;    // 8*3*128*32       = 98304 floats
static const size_t WS_D3 = 147456;   // 4*3*80*32        = 30720 floats -> end 178176

// scaled f16 split: v = hi + lo * 2^-12, error ~2^-24 relative (f32-grade).
__device__ inline void f2h2(float v, short& hi, short& lo) {
    _Float16 h = (_Float16)v;
    float r = (v - (float)h) * 4096.0f;
    _Float16 l = (_Float16)r;
    hi = __builtin_bit_cast(short, h);
    lo = __builtin_bit_cast(short, l);
}

// fill split-weight fragments: dst layout [(c*KS+k)*2+p][co][32 ci-shorts]
// e over NCH*KS*C_OUT*32 elements (hi+lo both written per element).
template<int C_IN, int C_OUT, int KS>
__device__ inline void wsplit_fill(const float* __restrict__ w,
                                   short* __restrict__ dst, int e) {
    int i  = e & 31;
    int r  = e >> 5;
    int co = r % C_OUT;
    int r2 = r / C_OUT;          // c*KS + k
    int k  = r2 % KS;
    int c  = r2 / KS;
    int ci = c * 32 + i;
    float v = (ci < C_IN) ? w[((size_t)co * C_IN + ci) * KS + k] : 0.f;
    short h, l; f2h2(v, h, l);
    size_t base = ((size_t)(c * KS + k) * 2 * C_OUT + co) * 32 + i;
    dst[base] = h;
    dst[base + (size_t)C_OUT * 32] = l;
}

__global__ __launch_bounds__(256) void prep_k(
        const float* __restrict__ w1, const float* __restrict__ w2,
        const float* __restrict__ w3, const float* __restrict__ cb,
        float* wsf) {
    int e = blockIdx.x * 256 + threadIdx.x;
    short* base = (short*)(wsf + OFF_WS);
    if (e < 36864)        wsplit_fill<80, 128, 3>(w1, (short*)(wsf + OFF_WS + WS_E1), e);
    else if (e < 135168)  wsplit_fill<128, 256, 3>(w2, (short*)(wsf + OFF_WS + WS_E2), e - 36864);
    else if (e < 151552)  wsplit_fill<256, 64, 1>(w3, (short*)(wsf + OFF_WS + WS_E3), e - 135168);
    else if (e < 152064) {
        int c = e - 151552;
        const float* p = cb + (size_t)c * 64;
        double s = 0.0;
        for (int d = 0; d < 64; ++d) { double v = p[d]; s += v * v; }
        wsf[OFF_C2 + c] = (float)s;
    } else if (e == 152064) {
        *(double*)(wsf + OFF_LOSS) = 0.0;
    }
    (void)base;
}

__global__ __launch_bounds__(256) void prep2_k(
        const float* __restrict__ wd1, const float* __restrict__ wd2,
        const float* __restrict__ wd3, float* wsf) {
    int e = blockIdx.x * 256 + threadIdx.x;
    if (e < 49152)        wsplit_fill<64, 256, 3>(wd1, (short*)(wsf + OFF_WS + WS_D1), e);
    else if (e < 147456)  wsplit_fill<256, 128, 3>(wd2, (short*)(wsf + OFF_WS + WS_D2), e - 49152);
    else if (e < 178176)  wsplit_fill<128, 80, 3>(wd3, (short*)(wsf + OFF_WS + WS_D3), e - 147456);
}

// ---- conv1d via scaled-f16 split MFMA; w-fragments direct global->VGPR ----
// GEMM M=co, N=t, K=ci per k-tap. Block: 64co x TT t, 4 waves (wave=16co strip).
// gfx950 16x16x32 maps (HW-verified r0/r1): A[m=lane&15][k=q*8+j],
// B[k=q*8+j][n=lane&15], D[m=q*4+r][n=lane&15].
// acc0 += ah*bh ; acc1 += ah*bl + al*bh ; out = acc0 + acc1*2^-12.
template<int C_IN, int C_OUT, int KS, bool BN_IN>
__global__ __launch_bounds__(256, 3) void fconv_k(
        const float* __restrict__ x, const short* __restrict__ wsp,
        const float* __restrict__ bias, const float2* __restrict__ stats,
        float* __restrict__ out) {
    constexpr int NCH  = (C_IN + 31) / 32;
    constexpr int HALO = KS / 2;
    constexpr int TT   = (KS == 1) ? 64 : 128;   // t-tile
    constexpr int NTT  = TT / 16;                // MFMA t-subtiles
    constexpr int NTILE = T_LEN / TT;
    constexpr int XR   = TT + KS - 1;
    constexpr int RS   = 72;                     // shorts/row (144B, 16B-aligned)
    constexpr int LO   = 40;                     // lo-plane offset within row
    constexpr int TQ   = TT / 4;                 // t-stride for 4-way load

    __shared__ __align__(16) short xs[XR * RS];

    const int tid  = threadIdx.x;
    const int lane = tid & 63;
    const int wv   = tid >> 6;
    const int ln   = lane & 15;
    const int q    = lane >> 4;

    const int n    = blockIdx.x / NTILE;
    const int t0   = (blockIdx.x % NTILE) * TT;
    const int co0  = blockIdx.y * 64;
    const int co_l = co0 + wv * 16 + ln;         // A-fragment row for this lane

    f32x4 a0[NTT], a1[NTT];
#pragma unroll
    for (int tt = 0; tt < NTT; ++tt)
#pragma unroll
        for (int i = 0; i < 4; ++i) { a0[tt][i] = 0.f; a1[tt][i] = 0.f; }

#pragma unroll 1
    for (int c = 0; c < NCH; ++c) {
        // ---- w fragments: direct global loads (L2-hot, coalesced 16B) ----
        half8 ah[KS], al[KS];
        {
            half8 z = {0, 0, 0, 0, 0, 0, 0, 0};
#pragma unroll
            for (int k = 0; k < KS; ++k) {
                const short* wp = wsp
                    + ((size_t)(c * KS + k) * 2 * C_OUT + co_l) * 32 + q * 8;
                ah[k] = (co_l < C_OUT) ? *(const half8*)wp : z;
                al[k] = (co_l < C_OUT) ? *(const half8*)(wp + (size_t)C_OUT * 32) : z;
            }
        }

        __syncthreads();
        // ---- stage x tile [t-row][ci] with split planes ----
        for (int e = tid; e < 32 * TQ; e += 256) {
            const int ci  = e / TQ;
            const int tq  = e % TQ;
            const int cig = c * 32 + ci;
            float v[4] = {0.f, 0.f, 0.f, 0.f};
            if (cig < C_IN) {
                const float* xp = x + ((size_t)(n * C_IN + cig)) * T_LEN + t0 + tq;
#pragma unroll
                for (int j = 0; j < 4; ++j) v[j] = xp[TQ * j];
                if constexpr (BN_IN) {
                    float2 s = stats[cig];
#pragma unroll
                    for (int j = 0; j < 4; ++j) v[j] = fmaxf(fmaf(v[j], s.x, s.y), 0.f);
                }
            }
#pragma unroll
            for (int j = 0; j < 4; ++j) {
                short h, l; f2h2(v[j], h, l);
                short* p = &xs[(HALO + tq + TQ * j) * RS + ci];
                p[0]  = h;
                p[LO] = l;
            }
        }
        if constexpr (KS == 3) {
            if (tid < 64) {
                const int ci   = tid & 31;
                const int side = tid >> 5;
                const int cig  = c * 32 + ci;
                const int gt   = side ? (t0 + TT) : (t0 - 1);
                float v = 0.f;
                if (cig < C_IN && gt >= 0 && gt < T_LEN) {
                    v = x[((size_t)(n * C_IN + cig)) * T_LEN + gt];
                    if constexpr (BN_IN) {
                        float2 s = stats[cig];
                        v = fmaxf(fmaf(v, s.x, s.y), 0.f);
                    }
                }
                short h, l; f2h2(v, h, l);
                short* p = &xs[(side ? (XR - 1) : 0) * RS + ci];
                p[0] = h; p[LO] = l;
            }
        }
        __syncthreads();

        // ---- MFMA: 3-product split ----
#pragma unroll
        for (int k = 0; k < KS; ++k) {
#pragma unroll
            for (int tt = 0; tt < NTT; ++tt) {
                const short* xr = &xs[(tt * 16 + ln + k) * RS + q * 8];
                half8 bh = *(const half8*)&xr[0];
                half8 bl = *(const half8*)&xr[LO];
                a0[tt] = __builtin_amdgcn_mfma_f32_16x16x32_f16(ah[k], bh, a0[tt], 0, 0, 0);
                a1[tt] = __builtin_amdgcn_mfma_f32_16x16x32_f16(ah[k], bl, a1[tt], 0, 0, 0);
                a1[tt] = __builtin_amdgcn_mfma_f32_16x16x32_f16(al[k], bh, a1[tt], 0, 0, 0);
            }
        }
    }

    // epilogue: lane reg r -> D[co = co0+wv*16+q*4+r][t = t0+tt*16+ln]
#pragma unroll
    for (int r = 0; r < 4; ++r) {
        const int co = co0 + wv * 16 + q * 4 + r;
        if (co < C_OUT) {
            const float bv = bias[co];
            float* op = out + ((size_t)(n * C_OUT + co)) * T_LEN + t0 + ln;
#pragma unroll
            for (int tt = 0; tt < NTT; ++tt)
                op[tt * 16] = fmaf(a1[tt][r], 0.000244140625f, a0[tt][r]) + bv;
        }
    }
}

// ---- BN stats stage 1 ----
__global__ __launch_bounds__(256) void stats1_k(
        const float* __restrict__ y, int C, double2* __restrict__ part) {
    int c = blockIdx.x % C, n = blockIdx.x / C;
    int tid = threadIdx.x;
    const float* p = y + ((size_t)(n * C + c)) * T_LEN;
    double s1 = 0.0, s2 = 0.0;
    for (int t = tid; t < T_LEN; t += 256) {
        double v = p[t];
        s1 += v; s2 += v * v;
    }
    __shared__ double r1[256], r2[256];
    r1[tid] = s1; r2[tid] = s2;
    __syncthreads();
    for (int s = 128; s > 0; s >>= 1) {
        if (tid < s) { r1[tid] += r1[tid + s]; r2[tid] += r2[tid + s]; }
        __syncthreads();
    }
    if (tid == 0) part[(size_t)c * N_B + n] = make_double2(r1[0], r2[0]);
}

// ---- BN stats stage 2: emit f32 (scale, shift) ----
__global__ __launch_bounds__(256) void stats2_k(
        const double2* __restrict__ part, int C, const float* __restrict__ g,
        const float* __restrict__ b, float2* __restrict__ stats) {
    int c = blockIdx.x * 256 + threadIdx.x;
    if (c >= C) return;
    double s1 = 0.0, s2 = 0.0;
    for (int n = 0; n < N_B; ++n) {
        double2 v = part[(size_t)c * N_B + n];
        s1 += v.x; s2 += v.y;
    }
    double m   = s1 / 65536.0;
    double var = s2 / 65536.0 - m * m;
    double sc  = (double)g[c] / sqrt(var + 1e-5);
    stats[c] = make_float2((float)sc, (float)((double)b[c] - m * sc));
}

// ---- VQ: replicate the reference's f32 d2 formula exactly ----
__global__ __launch_bounds__(256) void vq_k(
        const float* z, const float* __restrict__ cb,
        const float* __restrict__ c2, float* q,
        float* __restrict__ idx_out, double* __restrict__ loss) {
    __shared__ __align__(16) float zs[64 * 68];
    __shared__ __align__(16) float cs[64 * 68];
    __shared__ float  szf[64];
    __shared__ float  redS[64 * 16];
    __shared__ int    redI[64 * 16];
    __shared__ int    idxs[64];
    __shared__ double dred[256];

    const int tid = threadIdx.x;
    const int tx  = tid & 15, ty = tid >> 4;
    const int n   = blockIdx.x >> 6;
    const int t0  = (blockIdx.x & 63) * 64;

    for (int e = tid; e < 4096; e += 256) {
        int t = e & 63, d = e >> 6;
        zs[t * 68 + d] = z[((size_t)(n * 64 + d)) * T_LEN + t0 + t];
    }
    __syncthreads();
    if (tid < 64) {
        double s = 0.0;
        const float* zr = &zs[tid * 68];
        for (int d = 0; d < 64; ++d) { double v = zr[d]; s += v * v; }
        szf[tid] = (float)s;
    }

    float best[4];
    int bidx[4];
#pragma unroll
    for (int i = 0; i < 4; ++i) { best[i] = 3.0e38f; bidx[i] = 1 << 30; }

    for (int ch = 0; ch < 8; ++ch) {
        __syncthreads();
        for (int e = tid; e < 4096; e += 256) {
            int d = e & 63, c = e >> 6;
            cs[c * 68 + d] = cb[((size_t)(ch * 64 + c)) * 64 + d];
        }
        __syncthreads();

        double acc[4][4];
#pragma unroll
        for (int i = 0; i < 4; ++i)
#pragma unroll
            for (int j = 0; j < 4; ++j) acc[i][j] = 0.0;

        for (int d = 0; d < 64; d += 4) {
            float4 zv[4], cv[4];
#pragma unroll
            for (int i = 0; i < 4; ++i)
                zv[i] = *(const float4*)&zs[(tx + 16 * i) * 68 + d];
#pragma unroll
            for (int j = 0; j < 4; ++j)
                cv[j] = *(const float4*)&cs[(ty + 16 * j) * 68 + d];
#pragma unroll
            for (int i = 0; i < 4; ++i)
#pragma unroll
                for (int j = 0; j < 4; ++j) {
                    acc[i][j] = fma((double)zv[i].x, (double)cv[j].x, acc[i][j]);
                    acc[i][j] = fma((double)zv[i].y, (double)cv[j].y, acc[i][j]);
                    acc[i][j] = fma((double)zv[i].z, (double)cv[j].z, acc[i][j]);
                    acc[i][j] = fma((double)zv[i].w, (double)cv[j].w, acc[i][j]);
                }
        }
#pragma unroll
        for (int j = 0; j < 4; ++j) {
            int cg = ch * 64 + ty + 16 * j;
            float cc = c2[cg];
#pragma unroll
            for (int i = 0; i < 4; ++i) {
                float m32 = (float)acc[i][j];
                float A   = szf[tx + 16 * i] + cc;
                float s   = A - 2.0f * m32;
                if (s < best[i] || (s == best[i] && cg < bidx[i])) {
                    best[i] = s; bidx[i] = cg;
                }
            }
        }
    }
#pragma unroll
    for (int i = 0; i < 4; ++i) {
        redS[(tx + 16 * i) * 16 + ty] = best[i];
        redI[(tx + 16 * i) * 16 + ty] = bidx[i];
    }
    __syncthreads();

    if (tid < 64) {
        int t = tid;
        float bs = 3.0e38f; int bi = 1 << 30;
        for (int y2 = 0; y2 < 16; ++y2) {
            float v = redS[t * 16 + y2];
            int vi  = redI[t * 16 + y2];
            if (v < bs || (v == bs && vi < bi)) { bs = v; bi = vi; }
        }
        idxs[t] = bi;
        idx_out[(size_t)n * T_LEN + t0 + t] = (float)bi;
    }
    __syncthreads();

    {
        int g = tid >> 6, t = tid & 63;
        int bi = idxs[t];
        double ls = 0.0;
        for (int dd = 0; dd < 16; ++dd) {
            int d = g * 16 + dd;
            float qv = cb[(size_t)bi * 64 + d];
            float zv = zs[t * 68 + d];
            double df = (double)qv - (double)zv;
            ls += df * df;
            q[((size_t)(n * 64 + d)) * T_LEN + t0 + t] = qv;
        }
        dred[tid] = ls;
    }
    __syncthreads();
    for (int s = 128; s > 0; s >>= 1) {
        if (tid < s) dred[tid] += dred[tid + s];
        __syncthreads();
    }
    if (tid == 0) atomicAdd(loss, dred[0]);
}

__global__ void fin_k(const double* __restrict__ loss, float* __restrict__ out) {
    if (threadIdx.x == 0 && blockIdx.x == 0)
        out[0] = (float)(1.25 * (*loss) / 4194304.0);
}

extern "C" void kernel_launch(void* const* d_in, const int* in_sizes, int n_in,
                              void* d_out, int out_size, void* d_ws, size_t ws_size,
                              hipStream_t stream) {
    const float* x      = (const float*)d_in[0];
    const float* enc_w1 = (const float*)d_in[1];
    const float* enc_b1 = (const float*)d_in[2];
    const float* bn1_g  = (const float*)d_in[3];
    const float* bn1_b  = (const float*)d_in[4];
    const float* enc_w2 = (const float*)d_in[5];
    const float* enc_b2 = (const float*)d_in[6];
    const float* bn2_g  = (const float*)d_in[7];
    const float* bn2_b  = (const float*)d_in[8];
    const float* enc_w3 = (const float*)d_in[9];
    const float* enc_b3 = (const float*)d_in[10];
    const float* cb     = (const float*)d_in[11];
    const float* dec_w1 = (const float*)d_in[12];
    const float* dec_b1 = (const float*)d_in[13];
    const float* dbn1_g = (const float*)d_in[14];
    const float* dbn1_b = (const float*)d_in[15];
    const float* dec_w2 = (const float*)d_in[16];
    const float* dec_b2 = (const float*)d_in[17];
    const float* dbn2_g = (const float*)d_in[18];
    const float* dbn2_b = (const float*)d_in[19];
    const float* dec_w3 = (const float*)d_in[20];
    const float* dec_b3 = (const float*)d_in[21];

    float* wsf   = (float*)d_ws;
    float* outf  = (float*)d_out;
    float* A     = wsf + OFF_A;
    float* Bb    = wsf + OFF_B;
    float* Z     = wsf + OFF_Z;
    float2* st   = (float2*)(wsf + OFF_ST);
    double* lossp = (double*)(wsf + OFF_LOSS);
    double2* partA = (double2*)A;
    double2* partB = (double2*)Bb;

    const short* wsE1 = (const short*)(wsf + OFF_WS + WS_E1);
    const short* wsE2 = (const short*)(wsf + OFF_WS + WS_E2);
    const short* wsE3 = (const short*)(wsf + OFF_WS + WS_E3);
    const short* wsD1 = (const short*)(wsf + OFF_WS + WS_D1);
    const short* wsD2 = (const short*)(wsf + OFF_WS + WS_D2);
    const short* wsD3 = (const short*)(wsf + OFF_WS + WS_D3);

    prep_k<<<595, 256, 0, stream>>>(enc_w1, enc_w2, enc_w3, cb, wsf);

    // encoder
    fconv_k<80, 128, 3, false><<<dim3(512, 2), 256, 0, stream>>>(
        x, wsE1, enc_b1, nullptr, A);
    stats1_k<<<128 * N_B, 256, 0, stream>>>(A, 128, partB);
    stats2_k<<<1, 256, 0, stream>>>(partB, 128, bn1_g, bn1_b, st);
    fconv_k<128, 256, 3, true><<<dim3(512, 4), 256, 0, stream>>>(
        A, wsE2, enc_b2, st, Bb);
    stats1_k<<<256 * N_B, 256, 0, stream>>>(Bb, 256, partA);
    stats2_k<<<1, 256, 0, stream>>>(partA, 256, bn2_g, bn2_b, st);
    fconv_k<256, 64, 1, true><<<dim3(1024, 1), 256, 0, stream>>>(
        Bb, wsE3, enc_b3, st, Z);

    // decoder splits overwrite (now-dead) encoder splits
    prep2_k<<<696, 256, 0, stream>>>(dec_w1, dec_w2, dec_w3, wsf);

    // vector quantizer — f32-formula scores, exact ref grid
    vq_k<<<1024, 256, 0, stream>>>(Z, cb, wsf + OFF_C2, Z,
                                   outf + 5242881, lossp);
    fin_k<<<1, 64, 0, stream>>>(lossp, outf + 5242880);

    // decoder
    fconv_k<64, 256, 3, false><<<dim3(512, 4), 256, 0, stream>>>(
        Z, wsD1, dec_b1, nullptr, Bb);
    stats1_k<<<256 * N_B, 256, 0, stream>>>(Bb, 256, partA);
    stats2_k<<<1, 256, 0, stream>>>(partA, 256, dbn1_g, dbn1_b, st);
    fconv_k<256, 128, 3, true><<<dim3(512, 2), 256, 0, stream>>>(
        Bb, wsD2, dec_b2, st, A);
    stats1_k<<<128 * N_B, 256, 0, stream>>>(A, 128, partB);
    stats2_k<<<1, 256, 0, stream>>>(partB, 128, dbn2_g, dbn2_b, st);
    fconv_k<128, 80, 3, true><<<dim3(512, 2), 256, 0, stream>>>(
        A, wsD3, dec_b3, st, outf);
}

// Round 3
// 412.446 us; speedup vs baseline: 3.2718x; 1.2386x over previous
//
#include <hip/hip_runtime.h>
#include <math.h>

#define N_B 16
#define T_LEN 4096

typedef float f32x4  __attribute__((ext_vector_type(4)));
typedef _Float16 half8 __attribute__((ext_vector_type(8)));

// ---- workspace layout (float offsets) ----
static const size_t OFF_A    = 0;            // 16*128*4096
static const size_t OFF_B    = 8388608;      // 16*256*4096
static const size_t OFF_Z    = 25165824;     // 16*64*4096
static const size_t OFF_WS   = 29360128;     // split-weight region
static const size_t OFF_CBS  = 29540352;     // codebook split (65536 floats)
static const size_t OFF_C2   = 29683712;
static const size_t OFF_ST   = 29684736;
static const size_t OFF_LOSS = 29685760;

// encoder split offsets (floats from OFF_WS); region reused by decoder after conv3
static const size_t WS_E1 = 0;        // 3*3*128*32 = 36864 floats
static const size_t WS_E2 = 36864;    // 4*3*256*32 = 98304 floats
static const size_t WS_E3 = 135168;   // 8*1*64*32  = 16384 floats -> end 151552
static const size_t WS_D1 = 0;        // 2*3*256*32 = 49152 floats
static const size_t WS_D2 = 49152;    // 8*3*128*32 = 98304 floats
static const size_t WS_D3 = 147456;   // 4*3*80*32  = 30720 floats -> end 178176

// scaled f16 split: v = hi + lo * 2^-12, error ~2^-24 relative (f32-grade).
__device__ inline void f2h2(float v, short& hi, short& lo) {
    _Float16 h = (_Float16)v;
    float r = (v - (float)h) * 4096.0f;
    _Float16 l = (_Float16)r;
    hi = __builtin_bit_cast(short, h);
    lo = __builtin_bit_cast(short, l);
}

// fill split-weight fragments: dst layout [(c*KS+k)*2+p][co][32 ci-shorts]
template<int C_IN, int C_OUT, int KS>
__device__ inline void wsplit_fill(const float* __restrict__ w,
                                   short* __restrict__ dst, int e) {
    int i  = e & 31;
    int r  = e >> 5;
    int co = r % C_OUT;
    int r2 = r / C_OUT;          // c*KS + k
    int k  = r2 % KS;
    int c  = r2 / KS;
    int ci = c * 32 + i;
    float v = (ci < C_IN) ? w[((size_t)co * C_IN + ci) * KS + k] : 0.f;
    short h, l; f2h2(v, h, l);
    size_t base = ((size_t)(c * KS + k) * 2 * C_OUT + co) * 32 + i;
    dst[base] = h;
    dst[base + (size_t)C_OUT * 32] = l;
}

__global__ __launch_bounds__(256) void prep_k(
        const float* __restrict__ w1, const float* __restrict__ w2,
        const float* __restrict__ w3, const float* __restrict__ cb,
        float* wsf) {
    int e = blockIdx.x * 256 + threadIdx.x;
    if (e < 36864)        wsplit_fill<80, 128, 3>(w1, (short*)(wsf + OFF_WS + WS_E1), e);
    else if (e < 135168)  wsplit_fill<128, 256, 3>(w2, (short*)(wsf + OFF_WS + WS_E2), e - 36864);
    else if (e < 151552)  wsplit_fill<256, 64, 1>(w3, (short*)(wsf + OFF_WS + WS_E3), e - 135168);
    else if (e < 152064) {
        int c = e - 151552;
        const float* p = cb + (size_t)c * 64;
        double s = 0.0;
        for (int d = 0; d < 64; ++d) { double v = p[d]; s += v * v; }
        wsf[OFF_C2 + c] = (float)s;
    } else if (e < 184832) {
        // codebook split fragments: [ks][plane][code][32 d-shorts]
        int e2   = e - 152064;          // (ks*512 + code)*32 + i
        int i    = e2 & 31;
        int r    = e2 >> 5;
        int code = r & 511;
        int ks   = r >> 9;              // 0..1
        float v  = cb[(size_t)code * 64 + ks * 32 + i];
        short h, l; f2h2(v, h, l);
        short* dst = (short*)(wsf + OFF_CBS);
        dst[((size_t)(ks * 2 + 0) * 512 + code) * 32 + i] = h;
        dst[((size_t)(ks * 2 + 1) * 512 + code) * 32 + i] = l;
    } else if (e == 184832) {
        *(double*)(wsf + OFF_LOSS) = 0.0;
    }
}

__global__ __launch_bounds__(256) void prep2_k(
        const float* __restrict__ wd1, const float* __restrict__ wd2,
        const float* __restrict__ wd3, float* wsf) {
    int e = blockIdx.x * 256 + threadIdx.x;
    if (e < 49152)        wsplit_fill<64, 256, 3>(wd1, (short*)(wsf + OFF_WS + WS_D1), e);
    else if (e < 147456)  wsplit_fill<256, 128, 3>(wd2, (short*)(wsf + OFF_WS + WS_D2), e - 49152);
    else if (e < 178176)  wsplit_fill<128, 80, 3>(wd3, (short*)(wsf + OFF_WS + WS_D3), e - 147456);
}

// ---- conv1d via scaled-f16 split MFMA; w-fragments direct global->VGPR ----
// GEMM M=co, N=t, K=ci per k-tap. Block: 64co x TT t, 4 waves (wave=16co strip).
// gfx950 16x16x32 maps (HW-verified r1/r2): A[m=lane&15][k=q*8+j],
// B[k=q*8+j][n=lane&15], D[m=q*4+r][n=lane&15].
template<int C_IN, int C_OUT, int KS, bool BN_IN>
__global__ __launch_bounds__(256, 3) void fconv_k(
        const float* __restrict__ x, const short* __restrict__ wsp,
        const float* __restrict__ bias, const float2* __restrict__ stats,
        float* __restrict__ out) {
    constexpr int NCH  = (C_IN + 31) / 32;
    constexpr int HALO = KS / 2;
    constexpr int TT   = (KS == 1) ? 64 : 128;   // t-tile
    constexpr int NTT  = TT / 16;                // MFMA t-subtiles
    constexpr int NTILE = T_LEN / TT;
    constexpr int XR   = TT + KS - 1;
    constexpr int RS   = 72;                     // shorts/row (144B, 16B-aligned)
    constexpr int LO   = 40;                     // lo-plane offset within row
    constexpr int TQ   = TT / 4;                 // t-stride for 4-way load

    __shared__ __align__(16) short xs[XR * RS];

    const int tid  = threadIdx.x;
    const int lane = tid & 63;
    const int wv   = tid >> 6;
    const int ln   = lane & 15;
    const int q    = lane >> 4;

    const int n    = blockIdx.x / NTILE;
    const int t0   = (blockIdx.x % NTILE) * TT;
    const int co0  = blockIdx.y * 64;
    const int co_l = co0 + wv * 16 + ln;         // A-fragment row for this lane

    f32x4 a0[NTT], a1[NTT];
#pragma unroll
    for (int tt = 0; tt < NTT; ++tt)
#pragma unroll
        for (int i = 0; i < 4; ++i) { a0[tt][i] = 0.f; a1[tt][i] = 0.f; }

#pragma unroll 1
    for (int c = 0; c < NCH; ++c) {
        // ---- w fragments: direct global loads (L2-hot, coalesced 16B) ----
        half8 ah[KS], al[KS];
        {
            half8 z = {0, 0, 0, 0, 0, 0, 0, 0};
#pragma unroll
            for (int k = 0; k < KS; ++k) {
                const short* wp = wsp
                    + ((size_t)(c * KS + k) * 2 * C_OUT + co_l) * 32 + q * 8;
                ah[k] = (co_l < C_OUT) ? *(const half8*)wp : z;
                al[k] = (co_l < C_OUT) ? *(const half8*)(wp + (size_t)C_OUT * 32) : z;
            }
        }

        __syncthreads();
        // ---- stage x tile [t-row][ci] with split planes ----
        for (int e = tid; e < 32 * TQ; e += 256) {
            const int ci  = e / TQ;
            const int tq  = e % TQ;
            const int cig = c * 32 + ci;
            float v[4] = {0.f, 0.f, 0.f, 0.f};
            if (cig < C_IN) {
                const float* xp = x + ((size_t)(n * C_IN + cig)) * T_LEN + t0 + tq;
#pragma unroll
                for (int j = 0; j < 4; ++j) v[j] = xp[TQ * j];
                if constexpr (BN_IN) {
                    float2 s = stats[cig];
#pragma unroll
                    for (int j = 0; j < 4; ++j) v[j] = fmaxf(fmaf(v[j], s.x, s.y), 0.f);
                }
            }
#pragma unroll
            for (int j = 0; j < 4; ++j) {
                short h, l; f2h2(v[j], h, l);
                short* p = &xs[(HALO + tq + TQ * j) * RS + ci];
                p[0]  = h;
                p[LO] = l;
            }
        }
        if constexpr (KS == 3) {
            if (tid < 64) {
                const int ci   = tid & 31;
                const int side = tid >> 5;
                const int cig  = c * 32 + ci;
                const int gt   = side ? (t0 + TT) : (t0 - 1);
                float v = 0.f;
                if (cig < C_IN && gt >= 0 && gt < T_LEN) {
                    v = x[((size_t)(n * C_IN + cig)) * T_LEN + gt];
                    if constexpr (BN_IN) {
                        float2 s = stats[cig];
                        v = fmaxf(fmaf(v, s.x, s.y), 0.f);
                    }
                }
                short h, l; f2h2(v, h, l);
                short* p = &xs[(side ? (XR - 1) : 0) * RS + ci];
                p[0] = h; p[LO] = l;
            }
        }
        __syncthreads();

        // ---- MFMA: 3-product split ----
#pragma unroll
        for (int k = 0; k < KS; ++k) {
#pragma unroll
            for (int tt = 0; tt < NTT; ++tt) {
                const short* xr = &xs[(tt * 16 + ln + k) * RS + q * 8];
                half8 bh = *(const half8*)&xr[0];
                half8 bl = *(const half8*)&xr[LO];
                a0[tt] = __builtin_amdgcn_mfma_f32_16x16x32_f16(ah[k], bh, a0[tt], 0, 0, 0);
                a1[tt] = __builtin_amdgcn_mfma_f32_16x16x32_f16(ah[k], bl, a1[tt], 0, 0, 0);
                a1[tt] = __builtin_amdgcn_mfma_f32_16x16x32_f16(al[k], bh, a1[tt], 0, 0, 0);
            }
        }
    }

    // epilogue: lane reg r -> D[co = co0+wv*16+q*4+r][t = t0+tt*16+ln]
#pragma unroll
    for (int r = 0; r < 4; ++r) {
        const int co = co0 + wv * 16 + q * 4 + r;
        if (co < C_OUT) {
            const float bv = bias[co];
            float* op = out + ((size_t)(n * C_OUT + co)) * T_LEN + t0 + ln;
#pragma unroll
            for (int tt = 0; tt < NTT; ++tt)
                op[tt * 16] = fmaf(a1[tt][r], 0.000244140625f, a0[tt][r]) + bv;
        }
    }
}

// ---- BN stats stage 1 ----
__global__ __launch_bounds__(256) void stats1_k(
        const float* __restrict__ y, int C, double2* __restrict__ part) {
    int c = blockIdx.x % C, n = blockIdx.x / C;
    int tid = threadIdx.x;
    const float* p = y + ((size_t)(n * C + c)) * T_LEN;
    double s1 = 0.0, s2 = 0.0;
    for (int t = tid; t < T_LEN; t += 256) {
        double v = p[t];
        s1 += v; s2 += v * v;
    }
    __shared__ double r1[256], r2[256];
    r1[tid] = s1; r2[tid] = s2;
    __syncthreads();
    for (int s = 128; s > 0; s >>= 1) {
        if (tid < s) { r1[tid] += r1[tid + s]; r2[tid] += r2[tid + s]; }
        __syncthreads();
    }
    if (tid == 0) part[(size_t)c * N_B + n] = make_double2(r1[0], r2[0]);
}

// ---- BN stats stage 2: emit f32 (scale, shift) ----
__global__ __launch_bounds__(256) void stats2_k(
        const double2* __restrict__ part, int C, const float* __restrict__ g,
        const float* __restrict__ b, float2* __restrict__ stats) {
    int c = blockIdx.x * 256 + threadIdx.x;
    if (c >= C) return;
    double s1 = 0.0, s2 = 0.0;
    for (int n = 0; n < N_B; ++n) {
        double2 v = part[(size_t)c * N_B + n];
        s1 += v.x; s2 += v.y;
    }
    double m   = s1 / 65536.0;
    double var = s2 / 65536.0 - m * m;
    double sc  = (double)g[c] / sqrt(var + 1e-5);
    stats[c] = make_float2((float)sc, (float)((double)b[c] - m * sc));
}

// ---- VQ via scaled-f16 split MFMA ----
// GEMM M=code(512), N=t(64/block), K=d(64). Block: 4 waves; wave wv owns
// t-subtile wv*16..+15 and sweeps all 512 codes (32 tiles x 2 k-steps x 3).
// Scores finished per tile; per-lane running argmin; shfl-xor merge over q.
__global__ __launch_bounds__(256) void vq_k(
        const float* __restrict__ z, const float* __restrict__ cb,
        const short* __restrict__ cbs, const float* __restrict__ c2,
        float* __restrict__ q, float* __restrict__ idx_out,
        double* __restrict__ loss) {
    __shared__ __align__(16) float zs[64 * 68];    // f32 tile [t][d] (szf/loss/q)
    __shared__ __align__(16) short zh[64 * 136];   // split tile [t][(ks*2+p)*32+i]
    __shared__ float  c2s[512];
    __shared__ float  szf_s[64];
    __shared__ int    idxs[64];
    __shared__ double dred[256];

    const int tid  = threadIdx.x;
    const int lane = tid & 63;
    const int wv   = tid >> 6;
    const int ln   = lane & 15;
    const int q4   = lane >> 4;
    const int n    = blockIdx.x >> 6;
    const int t0   = (blockIdx.x & 63) * 64;

    // ---- stage z tile (f32 + split planes) and c2 ----
    for (int e = tid; e < 512; e += 256) c2s[e] = c2[e];
    for (int e = tid; e < 1024; e += 256) {
        const int d  = e >> 4;
        const int tq = e & 15;
        const float* zp = z + ((size_t)(n * 64 + d)) * T_LEN + t0 + tq;
        const int ks = d >> 5, i = d & 31;
#pragma unroll
        for (int j = 0; j < 4; ++j) {
            const int t = tq + 16 * j;
            float v = zp[16 * j];
            zs[t * 68 + d] = v;
            short h, l; f2h2(v, h, l);
            zh[t * 136 + (ks * 2 + 0) * 32 + i] = h;
            zh[t * 136 + (ks * 2 + 1) * 32 + i] = l;
        }
    }
    __syncthreads();
    if (tid < 64) {
        double s = 0.0;
        const float* zr = &zs[tid * 68];
        for (int d = 0; d < 64; ++d) { double v = zr[d]; s += v * v; }
        szf_s[tid] = (float)s;
    }
    __syncthreads();

    // ---- B fragments for this wave's t = wv*16+ln (fixed across all codes) ----
    const short* zr = &zh[(wv * 16 + ln) * 136 + q4 * 8];
    const half8 bh0 = *(const half8*)&zr[0];
    const half8 bl0 = *(const half8*)&zr[32];
    const half8 bh1 = *(const half8*)&zr[64];
    const half8 bl1 = *(const half8*)&zr[96];
    const float As  = szf_s[wv * 16 + ln];

    float bs = 3.0e38f;
    int   bi = 1 << 30;

#pragma unroll 4
    for (int ct = 0; ct < 32; ++ct) {
        const short* ap = cbs + ((size_t)(ct * 16 + ln)) * 32 + q4 * 8;
        const half8 ah0 = *(const half8*)&ap[0];
        const half8 al0 = *(const half8*)&ap[512 * 32];
        const half8 ah1 = *(const half8*)&ap[2 * 512 * 32];
        const half8 al1 = *(const half8*)&ap[3 * 512 * 32];
        f32x4 a0 = {0.f, 0.f, 0.f, 0.f};
        f32x4 a1 = {0.f, 0.f, 0.f, 0.f};
        a0 = __builtin_amdgcn_mfma_f32_16x16x32_f16(ah0, bh0, a0, 0, 0, 0);
        a1 = __builtin_amdgcn_mfma_f32_16x16x32_f16(ah0, bl0, a1, 0, 0, 0);
        a1 = __builtin_amdgcn_mfma_f32_16x16x32_f16(al0, bh0, a1, 0, 0, 0);
        a0 = __builtin_amdgcn_mfma_f32_16x16x32_f16(ah1, bh1, a0, 0, 0, 0);
        a1 = __builtin_amdgcn_mfma_f32_16x16x32_f16(ah1, bl1, a1, 0, 0, 0);
        a1 = __builtin_amdgcn_mfma_f32_16x16x32_f16(al1, bh1, a1, 0, 0, 0);
#pragma unroll
        for (int r = 0; r < 4; ++r) {
            const int code = ct * 16 + q4 * 4 + r;   // D: m = q*4+r
            const float m32 = fmaf(a1[r], 0.000244140625f, a0[r]);
            const float A   = As + c2s[code];
            const float s   = A - 2.0f * m32;
            if (s < bs || (s == bs && code < bi)) { bs = s; bi = code; }
        }
    }
    // merge the 4 lanes (q4 groups) holding the same t
#pragma unroll
    for (int off = 16; off <= 32; off <<= 1) {
        const float os = __shfl_xor(bs, off);
        const int   oi = __shfl_xor(bi, off);
        if (os < bs || (os == bs && oi < bi)) { bs = os; bi = oi; }
    }
    if (q4 == 0) {
        const int t = wv * 16 + ln;
        idxs[t] = bi;
        idx_out[(size_t)n * T_LEN + t0 + t] = (float)bi;
    }
    __syncthreads();

    // ---- quantized write + loss (unchanged, f64 exact) ----
    {
        const int g = tid >> 6, t = tid & 63;
        const int bi2 = idxs[t];
        double ls = 0.0;
        for (int dd = 0; dd < 16; ++dd) {
            const int d = g * 16 + dd;
            const float qv = cb[(size_t)bi2 * 64 + d];
            const float zv = zs[t * 68 + d];
            const double df = (double)qv - (double)zv;
            ls += df * df;
            q[((size_t)(n * 64 + d)) * T_LEN + t0 + t] = qv;
        }
        dred[tid] = ls;
    }
    __syncthreads();
    for (int s = 128; s > 0; s >>= 1) {
        if (tid < s) dred[tid] += dred[tid + s];
        __syncthreads();
    }
    if (tid == 0) atomicAdd(loss, dred[0]);
}

__global__ void fin_k(const double* __restrict__ loss, float* __restrict__ out) {
    if (threadIdx.x == 0 && blockIdx.x == 0)
        out[0] = (float)(1.25 * (*loss) / 4194304.0);
}

extern "C" void kernel_launch(void* const* d_in, const int* in_sizes, int n_in,
                              void* d_out, int out_size, void* d_ws, size_t ws_size,
                              hipStream_t stream) {
    const float* x      = (const float*)d_in[0];
    const float* enc_w1 = (const float*)d_in[1];
    const float* enc_b1 = (const float*)d_in[2];
    const float* bn1_g  = (const float*)d_in[3];
    const float* bn1_b  = (const float*)d_in[4];
    const float* enc_w2 = (const float*)d_in[5];
    const float* enc_b2 = (const float*)d_in[6];
    const float* bn2_g  = (const float*)d_in[7];
    const float* bn2_b  = (const float*)d_in[8];
    const float* enc_w3 = (const float*)d_in[9];
    const float* enc_b3 = (const float*)d_in[10];
    const float* cb     = (const float*)d_in[11];
    const float* dec_w1 = (const float*)d_in[12];
    const float* dec_b1 = (const float*)d_in[13];
    const float* dbn1_g = (const float*)d_in[14];
    const float* dbn1_b = (const float*)d_in[15];
    const float* dec_w2 = (const float*)d_in[16];
    const float* dec_b2 = (const float*)d_in[17];
    const float* dbn2_g = (const float*)d_in[18];
    const float* dbn2_b = (const float*)d_in[19];
    const float* dec_w3 = (const float*)d_in[20];
    const float* dec_b3 = (const float*)d_in[21];

    float* wsf   = (float*)d_ws;
    float* outf  = (float*)d_out;
    float* A     = wsf + OFF_A;
    float* Bb    = wsf + OFF_B;
    float* Z     = wsf + OFF_Z;
    float2* st   = (float2*)(wsf + OFF_ST);
    double* lossp = (double*)(wsf + OFF_LOSS);
    double2* partA = (double2*)A;
    double2* partB = (double2*)Bb;

    const short* wsE1 = (const short*)(wsf + OFF_WS + WS_E1);
    const short* wsE2 = (const short*)(wsf + OFF_WS + WS_E2);
    const short* wsE3 = (const short*)(wsf + OFF_WS + WS_E3);
    const short* wsD1 = (const short*)(wsf + OFF_WS + WS_D1);
    const short* wsD2 = (const short*)(wsf + OFF_WS + WS_D2);
    const short* wsD3 = (const short*)(wsf + OFF_WS + WS_D3);
    const short* cbs  = (const short*)(wsf + OFF_CBS);

    prep_k<<<723, 256, 0, stream>>>(enc_w1, enc_w2, enc_w3, cb, wsf);

    // encoder
    fconv_k<80, 128, 3, false><<<dim3(512, 2), 256, 0, stream>>>(
        x, wsE1, enc_b1, nullptr, A);
    stats1_k<<<128 * N_B, 256, 0, stream>>>(A, 128, partB);
    stats2_k<<<1, 256, 0, stream>>>(partB, 128, bn1_g, bn1_b, st);
    fconv_k<128, 256, 3, true><<<dim3(512, 4), 256, 0, stream>>>(
        A, wsE2, enc_b2, st, Bb);
    stats1_k<<<256 * N_B, 256, 0, stream>>>(Bb, 256, partA);
    stats2_k<<<1, 256, 0, stream>>>(partA, 256, bn2_g, bn2_b, st);
    fconv_k<256, 64, 1, true><<<dim3(1024, 1), 256, 0, stream>>>(
        Bb, wsE3, enc_b3, st, Z);

    // decoder splits overwrite (now-dead) encoder splits
    prep2_k<<<696, 256, 0, stream>>>(dec_w1, dec_w2, dec_w3, wsf);

    // vector quantizer — split-f16 MFMA scores, same f32 finish formula
    vq_k<<<1024, 256, 0, stream>>>(Z, cb, cbs, wsf + OFF_C2, Z,
                                   outf + 5242881, lossp);
    fin_k<<<1, 64, 0, stream>>>(lossp, outf + 5242880);

    // decoder
    fconv_k<64, 256, 3, false><<<dim3(512, 4), 256, 0, stream>>>(
        Z, wsD1, dec_b1, nullptr, Bb);
    stats1_k<<<256 * N_B, 256, 0, stream>>>(Bb, 256, partA);
    stats2_k<<<1, 256, 0, stream>>>(partA, 256, dbn1_g, dbn1_b, st);
    fconv_k<256, 128, 3, true><<<dim3(512, 2), 256, 0, stream>>>(
        Bb, wsD2, dec_b2, st, A);
    stats1_k<<<128 * N_B, 256, 0, stream>>>(A, 128, partB);
    stats2_k<<<1, 256, 0, stream>>>(partB, 128, dbn2_g, dbn2_b, st);
    fconv_k<128, 80, 3, true><<<dim3(512, 2), 256, 0, stream>>>(
        A, wsD3, dec_b3, st, outf);
}